// Round 1
// baseline (162.248 us; speedup 1.0000x reference)
//
#include <hip/hip_runtime.h>
#include <math.h>

// TransE multi_tails scoring: out[b, n] = -||(E[heads[b]] + R[relations[b]]) - E[tails[n]]||_2
// B=128, N_CAND=10000, D=256, all f32.
//
// Single fused kernel, GEMM-shaped tiling:
//   BM=64 (heads) x BN=64 (tails) x BK=16, 256 threads, 4x4 register tile/thread.
//   A-tile (h+r) computed on the fly during staging; B-tile = gathered tail rows.
//   Tiles stored k-major [BK][tile] so inner reads are ds_read_b128
//   (A: 16-way broadcast = free; B: 2-way bank alias = free per m136).
//   Staging mapping srow=tid&63 -> conflict-free LDS stores, coalesced idx loads.

#define NUM_HEADS 128
#define NCAND     10000
#define EDIM      256
#define BM        64
#define BN        64
#define BK        16

__global__ __launch_bounds__(256) void transe_score_kernel(
    const float* __restrict__ entity,
    const float* __restrict__ relation,
    const int*   __restrict__ heads,
    const int*   __restrict__ relations,
    const int*   __restrict__ tails,
    float*       __restrict__ out)
{
    __shared__ float As[BK][BM];   // left (h+r), k-major
    __shared__ float Bs[BK][BN];   // tail rows, k-major

    const int tid = threadIdx.x;
    const int n0  = blockIdx.x * BN;   // tail tile
    const int m0  = blockIdx.y * BM;   // head tile (0 or 64)

    // ---- staging mapping: srow = row within tile (0..63), skq = which float4 of BK
    const int srow = tid & 63;
    const int skq  = tid >> 6;         // 0..3, k offset = skq*4

    // A row pointers (always valid: NUM_HEADS = 2*BM)
    const int am = m0 + srow;
    const float* __restrict__ pah = entity   + (size_t)heads[am]     * EDIM;
    const float* __restrict__ par = relation + (size_t)relations[am] * EDIM;

    // B row pointer (tail gather), clamped for the partial last tile
    int bn = n0 + srow;
    if (bn > NCAND - 1) bn = NCAND - 1;
    const float* __restrict__ pb = entity + (size_t)tails[bn] * EDIM;

    // ---- compute mapping: 4x4 micro-tile
    const int tx = tid & 15;   // n direction, *4
    const int ty = tid >> 4;   // m direction, *4

    float acc[4][4] = {};

    for (int k0 = 0; k0 < EDIM; k0 += BK) {
        // stage A = h + r, transposed to [k][m]
        float4 vh = *reinterpret_cast<const float4*>(pah + k0 + skq * 4);
        float4 vr = *reinterpret_cast<const float4*>(par + k0 + skq * 4);
        As[skq * 4 + 0][srow] = vh.x + vr.x;
        As[skq * 4 + 1][srow] = vh.y + vr.y;
        As[skq * 4 + 2][srow] = vh.z + vr.z;
        As[skq * 4 + 3][srow] = vh.w + vr.w;
        // stage B
        float4 vb = *reinterpret_cast<const float4*>(pb + k0 + skq * 4);
        Bs[skq * 4 + 0][srow] = vb.x;
        Bs[skq * 4 + 1][srow] = vb.y;
        Bs[skq * 4 + 2][srow] = vb.z;
        Bs[skq * 4 + 3][srow] = vb.w;
        __syncthreads();

        #pragma unroll
        for (int kk = 0; kk < BK; ++kk) {
            float4 a4 = *reinterpret_cast<const float4*>(&As[kk][ty * 4]);
            float4 b4 = *reinterpret_cast<const float4*>(&Bs[kk][tx * 4]);
            float a[4] = {a4.x, a4.y, a4.z, a4.w};
            float b[4] = {b4.x, b4.y, b4.z, b4.w};
            #pragma unroll
            for (int i = 0; i < 4; ++i)
                #pragma unroll
                for (int j = 0; j < 4; ++j) {
                    float d = a[i] - b[j];
                    acc[i][j] = fmaf(d, d, acc[i][j]);
                }
        }
        __syncthreads();
    }

    // ---- epilogue: out[m][n] = -sqrt(acc)
    const int n = n0 + tx * 4;
    if (n < NCAND) {   // 4 | NCAND, so a float4 never straddles the edge
        #pragma unroll
        for (int i = 0; i < 4; ++i) {
            const int m = m0 + ty * 4 + i;
            float4 o;
            o.x = -sqrtf(acc[i][0]);
            o.y = -sqrtf(acc[i][1]);
            o.z = -sqrtf(acc[i][2]);
            o.w = -sqrtf(acc[i][3]);
            *reinterpret_cast<float4*>(out + (size_t)m * NCAND + n) = o;
        }
    }
}

extern "C" void kernel_launch(void* const* d_in, const int* in_sizes, int n_in,
                              void* d_out, int out_size, void* d_ws, size_t ws_size,
                              hipStream_t stream) {
    const float* entity    = (const float*)d_in[0];
    const float* relation  = (const float*)d_in[1];
    const int*   heads     = (const int*)d_in[2];
    const int*   relations = (const int*)d_in[3];
    const int*   tails     = (const int*)d_in[4];
    float*       out       = (float*)d_out;

    const int n_tiles = (NCAND + BN - 1) / BN;      // 157
    const int m_tiles = NUM_HEADS / BM;             // 2
    dim3 grid(n_tiles, m_tiles);
    dim3 block(256);
    transe_score_kernel<<<grid, block, 0, stream>>>(entity, relation, heads,
                                                    relations, tails, out);
}

// Round 2
// 160.602 us; speedup vs baseline: 1.0102x; 1.0102x over previous
//
#include <hip/hip_runtime.h>
#include <math.h>

// TransE multi_tails: out[m][n] = -||(E[heads[m]]+R[relations[m]]) - E[tails[n]]||_2
// B=128, N_CAND=10000, D=256, f32.
//
// Decomposition: ||l-t||^2 = ||l||^2 + ||t||^2 - 2*dot(l,t)  -> pure-FMA GEMM.
// Kernel 1 (prep): build leftT[256][128] (k-major), gather tails into TT[256][10048]
//   (k-major, contiguous), plus 4-way partial squared norms. All into d_ws (~10.6 MB).
// Kernel 2 (gemm): 64x64x(BK=32) tiles, 256 thr, 4x4 micro-tile, double-buffered LDS
//   staged via global_load_lds width=16 (wave-uniform LDS dest + per-lane global src),
//   T3-minimum pipeline: STAGE(next); COMPUTE(cur); vmcnt(0); barrier  (1 barrier/step).

#define NHEADS   128
#define NCAND    10000
#define NPAD     10048        // padded tail count (157*64), 16B-aligned row stride
#define EDIM     256
#define BM       64
#define BN       64
#define BK       32
#define KSTEPS   (EDIM / BK)  // 8

// ws layout (float offsets)
#define TT_OFF   0
#define LT_OFF   (EDIM * NPAD)                 // 2,572,288
#define TP_OFF   (LT_OFF + EDIM * NHEADS)      // + 32,768
#define LP_OFF   (TP_OFF + 4 * NPAD)           // + 40,192
// total floats = LP_OFF + 4*NHEADS ~= 2,645,760  (~10.6 MB)

#define GLL(gsrc, ldst) \
  __builtin_amdgcn_global_load_lds( \
      (const __attribute__((address_space(1))) void*)(gsrc), \
      (__attribute__((address_space(3))) void*)(ldst), 16, 0, 0)

// ---------------- Kernel 1: gather/transpose + partial norms ----------------
__global__ __launch_bounds__(256) void transe_prep(
    const float* __restrict__ entity, const float* __restrict__ relation,
    const int* __restrict__ heads, const int* __restrict__ relations,
    const int* __restrict__ tails, float* __restrict__ ws)
{
    float* __restrict__ TT = ws + TT_OFF;
    float* __restrict__ LT = ws + LT_OFF;
    float* __restrict__ TP = ws + TP_OFF;
    float* __restrict__ LP = ws + LP_OFF;

    const int tid  = threadIdx.x;
    const int lane = tid & 63;
    const int kc   = tid >> 6;          // 0..3, owns k in [64*kc, 64*kc+63]
    const int b    = blockIdx.x;

    if (b < 157) {                       // tail rows
        const int n = b * 64 + lane;
        if (n >= NCAND) return;          // no barriers in this kernel
        const float* __restrict__ row = entity + (size_t)tails[n] * EDIM;
        float p = 0.f;
        #pragma unroll
        for (int i = 0; i < 16; ++i) {
            const int k = kc * 64 + i * 4;
            float4 v = *reinterpret_cast<const float4*>(row + k);
            TT[(size_t)(k + 0) * NPAD + n] = v.x;   // coalesced across lane=n
            TT[(size_t)(k + 1) * NPAD + n] = v.y;
            TT[(size_t)(k + 2) * NPAD + n] = v.z;
            TT[(size_t)(k + 3) * NPAD + n] = v.w;
            p = fmaf(v.x, v.x, p); p = fmaf(v.y, v.y, p);
            p = fmaf(v.z, v.z, p); p = fmaf(v.w, v.w, p);
        }
        TP[kc * NPAD + n] = p;
    } else {                             // left rows: l = h + r
        const int m = (b - 157) * 64 + lane;   // b=157 -> 0..63, b=158 -> 64..127
        const float* __restrict__ eh = entity   + (size_t)heads[m]     * EDIM;
        const float* __restrict__ rr = relation + (size_t)relations[m] * EDIM;
        float p = 0.f;
        #pragma unroll
        for (int i = 0; i < 16; ++i) {
            const int k = kc * 64 + i * 4;
            float4 a = *reinterpret_cast<const float4*>(eh + k);
            float4 c = *reinterpret_cast<const float4*>(rr + k);
            float4 s;
            s.x = a.x + c.x; s.y = a.y + c.y; s.z = a.z + c.z; s.w = a.w + c.w;
            LT[(k + 0) * NHEADS + m] = s.x;
            LT[(k + 1) * NHEADS + m] = s.y;
            LT[(k + 2) * NHEADS + m] = s.z;
            LT[(k + 3) * NHEADS + m] = s.w;
            p = fmaf(s.x, s.x, p); p = fmaf(s.y, s.y, p);
            p = fmaf(s.z, s.z, p); p = fmaf(s.w, s.w, p);
        }
        LP[kc * NHEADS + m] = p;
    }
}

// ---------------- Kernel 2: dot GEMM + epilogue ----------------
__global__ __launch_bounds__(256) void transe_gemm(
    const float* __restrict__ ws, float* __restrict__ out)
{
    const float* __restrict__ TT = ws + TT_OFF;
    const float* __restrict__ LT = ws + LT_OFF;
    const float* __restrict__ TP = ws + TP_OFF;
    const float* __restrict__ LP = ws + LP_OFF;

    __shared__ float As[2][BK][BM];   // 8 KB each buf
    __shared__ float Bs[2][BK][BN];   // 8 KB each buf   (total 32 KB)

    const int tid = threadIdx.x;
    const int w   = tid >> 6;          // wave 0..3
    const int l   = tid & 63;
    const int kr  = l >> 4;            // k-row within one wave-instr (0..3)
    const int cq  = (l & 15) * 4;      // column quad within tile row
    const int n0  = blockIdx.x * BN;
    const int m0  = blockIdx.y * BM;
    const int tx  = tid & 15;          // n direction (x4)
    const int ty  = tid >> 4;          // m direction (x4)

    float acc[4][4] = {};

    // One wave-instr covers 4 k-rows x 64 cols (1 KB). Wave w, j in {0,1}:
    // k-rows [4w+16j .. 4w+16j+3]; lane l -> (k=+kr, col=cq). LDS dest is
    // wave-uniform row base; HW adds lane*16B -> exactly [kr][cq]. (m104)
    #define STAGE(step, buf)                                                    \
        {                                                                       \
            const int k0_ = (step) * BK;                                        \
            _Pragma("unroll")                                                   \
            for (int j = 0; j < 2; ++j) {                                       \
                const int kl = 4 * w + 16 * j;                                  \
                const float* sA = LT + (size_t)(k0_ + kl + kr) * NHEADS + m0 + cq; \
                const float* sB = TT + (size_t)(k0_ + kl + kr) * NPAD   + n0 + cq; \
                GLL(sA, &As[buf][kl][0]);                                       \
                GLL(sB, &Bs[buf][kl][0]);                                       \
            }                                                                   \
        }

    STAGE(0, 0);
    asm volatile("s_waitcnt vmcnt(0)" ::: "memory");
    __builtin_amdgcn_s_barrier();

    for (int t = 0; t < KSTEPS; ++t) {
        const int buf = t & 1;
        if (t < KSTEPS - 1) STAGE(t + 1, buf ^ 1);   // issue-early: hides under FMAs
        #pragma unroll
        for (int kk = 0; kk < BK; ++kk) {
            float4 a4 = *reinterpret_cast<const float4*>(&As[buf][kk][ty * 4]);
            float4 b4 = *reinterpret_cast<const float4*>(&Bs[buf][kk][tx * 4]);
            float a[4] = {a4.x, a4.y, a4.z, a4.w};
            float b[4] = {b4.x, b4.y, b4.z, b4.w};
            #pragma unroll
            for (int i = 0; i < 4; ++i)
                #pragma unroll
                for (int jj = 0; jj < 4; ++jj)
                    acc[i][jj] = fmaf(a[i], b[jj], acc[i][jj]);
        }
        asm volatile("s_waitcnt vmcnt(0)" ::: "memory");  // next tile landed
        __builtin_amdgcn_s_barrier();                     // all waves done w/ cur
    }

    // epilogue: out = -sqrt(max(||l||^2 + ||t||^2 - 2*dot, 0))
    const int n = n0 + tx * 4;
    float4 tn = {0.f, 0.f, 0.f, 0.f};
    #pragma unroll
    for (int c = 0; c < 4; ++c) {
        float4 v = *reinterpret_cast<const float4*>(TP + c * NPAD + n);
        tn.x += v.x; tn.y += v.y; tn.z += v.z; tn.w += v.w;
    }
    if (n < NCAND) {                    // 4 | NCAND: float4 never straddles edge
        #pragma unroll
        for (int i = 0; i < 4; ++i) {
            const int m = m0 + ty * 4 + i;
            const float ln = LP[0 * NHEADS + m] + LP[1 * NHEADS + m] +
                             LP[2 * NHEADS + m] + LP[3 * NHEADS + m];
            float4 o;
            o.x = -sqrtf(fmaxf(ln + tn.x - 2.f * acc[i][0], 0.f));
            o.y = -sqrtf(fmaxf(ln + tn.y - 2.f * acc[i][1], 0.f));
            o.z = -sqrtf(fmaxf(ln + tn.z - 2.f * acc[i][2], 0.f));
            o.w = -sqrtf(fmaxf(ln + tn.w - 2.f * acc[i][3], 0.f));
            *reinterpret_cast<float4*>(out + (size_t)m * NCAND + n) = o;
        }
    }
}

extern "C" void kernel_launch(void* const* d_in, const int* in_sizes, int n_in,
                              void* d_out, int out_size, void* d_ws, size_t ws_size,
                              hipStream_t stream) {
    const float* entity    = (const float*)d_in[0];
    const float* relation  = (const float*)d_in[1];
    const int*   heads     = (const int*)d_in[2];
    const int*   relations = (const int*)d_in[3];
    const int*   tails     = (const int*)d_in[4];
    float*       ws        = (float*)d_ws;
    float*       out       = (float*)d_out;

    transe_prep<<<dim3(159), dim3(256), 0, stream>>>(entity, relation, heads,
                                                     relations, tails, ws);
    transe_gemm<<<dim3(157, 2), dim3(256), 0, stream>>>(ws, out);
}

// Round 3
// 153.142 us; speedup vs baseline: 1.0595x; 1.0487x over previous
//
#include <hip/hip_runtime.h>
#include <math.h>

// TransE multi_tails: out[m][n] = -||(E[heads[m]]+R[relations[m]]) - E[tails[n]]||_2
// B=128, N_CAND=10000, D=256, f32 in/out.
//
// ||l-t||^2 = ||l||^2 + ||t||^2 - 2*dot(l,t).  dot via SPLIT-BF16 MFMA:
//   a = hi + lo (bf16 each);  dot ~= hi*hi + hi*lo + lo*hi  (3 passes of
//   mfma_f32_16x16x32_bf16, f32 accum; lo*lo dropped -> rel err ~2^-17).
// Prep: gather+split tails/left into row-major k-contiguous bf16 arrays + f32 norms.
// GEMM: 64x64 tile, 4 waves, double-buffered LDS staged via global_load_lds w=16.
//   Fragment reads: per wave 16 rows x 64 B = contiguous 1 KB -> conflict-free.

#define NHEADS 128
#define NCAND  10000
#define NPAD   10048          // 157 * 64
#define EDIM   256
#define BM     64
#define BN     64
#define BK     32
#define KSTEPS (EDIM / BK)    // 8

// ws byte offsets (all 16B-aligned)
#define THI_B  0
#define TLO_B  (NPAD * EDIM * 2)               //  5,144,576
#define LHI_B  (TLO_B + NPAD * EDIM * 2)       // 10,289,152
#define LLO_B  (LHI_B + NHEADS * EDIM * 2)     // 10,354,688
#define TP_B   (LLO_B + NHEADS * EDIM * 2)     // 10,420,224
#define LP_B   (TP_B + NPAD * 4)               // 10,460,416

typedef __attribute__((ext_vector_type(8))) short bf16x8;
typedef __attribute__((ext_vector_type(4))) float f32x4;

__device__ inline unsigned short bf16_rn(float x, float& back) {
    unsigned int u = __float_as_uint(x);
    unsigned int r = (u + 0x7FFFu + ((u >> 16) & 1u)) >> 16;
    back = __uint_as_float(r << 16);
    return (unsigned short)r;
}

// ---------------- Kernel 1: gather + bf16 hi/lo split + norms ----------------
__global__ __launch_bounds__(256) void transe_prep(
    const float* __restrict__ entity, const float* __restrict__ relation,
    const int* __restrict__ heads, const int* __restrict__ relations,
    const int* __restrict__ tails, char* __restrict__ ws)
{
    short* __restrict__ Thi = (short*)(ws + THI_B);
    short* __restrict__ Tlo = (short*)(ws + TLO_B);
    short* __restrict__ Lhi = (short*)(ws + LHI_B);
    short* __restrict__ Llo = (short*)(ws + LLO_B);
    float* __restrict__ TP  = (float*)(ws + TP_B);
    float* __restrict__ LP  = (float*)(ws + LP_B);

    __shared__ float pn[64][4];

    const int tid  = threadIdx.x;
    const int lane = tid & 63;
    const int kc   = tid >> 6;           // 0..3, owns k in [64kc, 64kc+64)
    const int b    = blockIdx.x;
    const bool isT = (b < 157);

    int row;
    const float* s0;
    const float* s1 = nullptr;
    short *dhi, *dlo;
    float* dp;
    if (isT) {
        row = b * 64 + lane;                       // 0..10047
        const int n = row > NCAND - 1 ? NCAND - 1 : row;   // clamp source only
        s0  = entity + (size_t)tails[n] * EDIM;
        dhi = Thi + (size_t)row * EDIM;
        dlo = Tlo + (size_t)row * EDIM;
        dp  = TP + row;
    } else {
        row = (b - 157) * 64 + lane;               // 0..127
        s0  = entity   + (size_t)heads[row]     * EDIM;
        s1  = relation + (size_t)relations[row] * EDIM;
        dhi = Lhi + (size_t)row * EDIM;
        dlo = Llo + (size_t)row * EDIM;
        dp  = LP + row;
    }

    float p = 0.f;
    #pragma unroll
    for (int q = 0; q < 8; ++q) {                  // 8 chunks of 8 floats
        const int k0 = kc * 64 + q * 8;
        float4 xa = *(const float4*)(s0 + k0);
        float4 xb = *(const float4*)(s0 + k0 + 4);
        float x[8] = {xa.x, xa.y, xa.z, xa.w, xb.x, xb.y, xb.z, xb.w};
        if (!isT) {
            float4 ya = *(const float4*)(s1 + k0);
            float4 yb = *(const float4*)(s1 + k0 + 4);
            x[0] += ya.x; x[1] += ya.y; x[2] += ya.z; x[3] += ya.w;
            x[4] += yb.x; x[5] += yb.y; x[6] += yb.z; x[7] += yb.w;
        }
        bf16x8 vhi, vlo;
        #pragma unroll
        for (int j = 0; j < 8; ++j) {
            float back;
            vhi[j] = (short)bf16_rn(x[j], back);
            float lo = x[j] - back;
            float lb;
            vlo[j] = (short)bf16_rn(lo, lb);
            p = fmaf(x[j], x[j], p);
        }
        *(bf16x8*)(dhi + k0) = vhi;
        *(bf16x8*)(dlo + k0) = vlo;
    }
    pn[lane][kc] = p;
    __syncthreads();
    if (kc == 0)
        *dp = pn[lane][0] + pn[lane][1] + pn[lane][2] + pn[lane][3];
}

// ---------------- Kernel 2: split-bf16 MFMA GEMM + epilogue ----------------
#define GLL(g, l_) __builtin_amdgcn_global_load_lds( \
    (const __attribute__((address_space(1))) void*)(g), \
    (__attribute__((address_space(3))) void*)(l_), 16, 0, 0)

__global__ __launch_bounds__(256) void transe_gemm(
    const char* __restrict__ ws, float* __restrict__ out)
{
    const short* __restrict__ Thi = (const short*)(ws + THI_B);
    const short* __restrict__ Tlo = (const short*)(ws + TLO_B);
    const short* __restrict__ Lhi = (const short*)(ws + LHI_B);
    const short* __restrict__ Llo = (const short*)(ws + LLO_B);
    const float* __restrict__ TP  = (const float*)(ws + TP_B);
    const float* __restrict__ LP  = (const float*)(ws + LP_B);

    // [buf][arr][row*BK + k]; arr: 0=Ahi 1=Alo 2=Bhi 3=Blo; 2048 shorts each; 32 KB total
    __shared__ short smem[2][4][BM * BK];

    const int tid = threadIdx.x;
    const int w   = tid >> 6;        // wave 0..3
    const int l   = tid & 63;
    const int n0  = blockIdx.x * BN;
    const int m0  = blockIdx.y * BM;

    // staging: wave w owns one array. Source row = base + 16j + (l>>2),
    // 16 B = 8 consecutive k at (l&3)*8. LDS dest wave-uniform, HW adds lane*16B:
    // j-th GLL fills rows 16j..16j+3? -> covers bytes [j*1024,(j+1)*1024) = rows 16j..16j+15. 
    const short* gbase;
    int rbase;
    if      (w == 0) { gbase = Lhi; rbase = m0; }
    else if (w == 1) { gbase = Llo; rbase = m0; }
    else if (w == 2) { gbase = Thi; rbase = n0; }
    else             { gbase = Tlo; rbase = n0; }
    const short* gl = gbase + (size_t)(rbase + (l >> 2)) * EDIM + (l & 3) * 8;
    short* ld0 = &smem[0][w][0];

    #define STAGE(t, buf)                                                   \
        {                                                                   \
            _Pragma("unroll")                                               \
            for (int j = 0; j < 4; ++j)                                     \
                GLL(gl + (size_t)(16 * j) * EDIM + (t) * BK,                \
                    ld0 + (buf) * 8192 + j * 512);                          \
        }

    f32x4 acc[4] = {};

    STAGE(0, 0);
    asm volatile("s_waitcnt vmcnt(0)" ::: "memory");
    __builtin_amdgcn_s_barrier();

    for (int t = 0; t < KSTEPS; ++t) {
        const int buf = t & 1;
        if (t < KSTEPS - 1) STAGE(t + 1, buf ^ 1);

        // fragments: lane l -> row (l&15), k = (l>>4)*8 .. +7 (one ds_read_b128).
        // A rows for wave w: 16w + (l&15).  One wave's read = contiguous 1 KB.
        const int fo = (l & 15) * BK + (l >> 4) * 8;
        bf16x8 ahi = *(const bf16x8*)(&smem[buf][0][16 * w * BK + fo]);
        bf16x8 alo = *(const bf16x8*)(&smem[buf][1][16 * w * BK + fo]);
        #pragma unroll
        for (int nf = 0; nf < 4; ++nf) {
            bf16x8 bhi = *(const bf16x8*)(&smem[buf][2][16 * nf * BK + fo]);
            bf16x8 blo = *(const bf16x8*)(&smem[buf][3][16 * nf * BK + fo]);
            acc[nf] = __builtin_amdgcn_mfma_f32_16x16x32_bf16(ahi, bhi, acc[nf], 0, 0, 0);
            acc[nf] = __builtin_amdgcn_mfma_f32_16x16x32_bf16(ahi, blo, acc[nf], 0, 0, 0);
            acc[nf] = __builtin_amdgcn_mfma_f32_16x16x32_bf16(alo, bhi, acc[nf], 0, 0, 0);
        }

        asm volatile("s_waitcnt vmcnt(0)" ::: "memory");
        __builtin_amdgcn_s_barrier();
    }

    // epilogue. C/D layout (m89-verified): col = lane&15, row = (lane>>4)*4 + reg.
    const int cb = l & 15;
    const int rq = l >> 4;
    #pragma unroll
    for (int nf = 0; nf < 4; ++nf) {
        const int col = n0 + 16 * nf + cb;
        if (col < NCAND) {
            const float tn = TP[col];
            #pragma unroll
            for (int r = 0; r < 4; ++r) {
                const int rowm = m0 + 16 * w + rq * 4 + r;
                const float v  = LP[rowm] + tn - 2.f * acc[nf][r];
                out[(size_t)rowm * NCAND + col] = -sqrtf(fmaxf(v, 0.f));
            }
        }
    }
}

extern "C" void kernel_launch(void* const* d_in, const int* in_sizes, int n_in,
                              void* d_out, int out_size, void* d_ws, size_t ws_size,
                              hipStream_t stream) {
    const float* entity    = (const float*)d_in[0];
    const float* relation  = (const float*)d_in[1];
    const int*   heads     = (const int*)d_in[2];
    const int*   relations = (const int*)d_in[3];
    const int*   tails     = (const int*)d_in[4];
    char*        ws        = (char*)d_ws;
    float*       out       = (float*)d_out;

    transe_prep<<<dim3(159), dim3(256), 0, stream>>>(entity, relation, heads,
                                                     relations, tails, ws);
    transe_gemm<<<dim3(157, 2), dim3(256), 0, stream>>>(ws, out);
}

// Round 6
// 149.838 us; speedup vs baseline: 1.0828x; 1.0220x over previous
//
#include <hip/hip_runtime.h>
#include <math.h>

// TransE multi_tails: out[m][n] = -||(E[heads[m]]+R[relations[m]]) - E[tails[n]]||_2
// B=128, N_CAND=10000, D=256, f32 in/out.
//
// Fully fused single kernel. ||l-t||^2 = ||l||^2 + ||t||^2 - 2*dot(l,t);
// dot via SPLIT-BF16 MFMA (hi*hi + hi*lo + lo*hi, f32 accum; rel err ~2^-17).
// Tile: BM=128 (all heads) x BN=64 x BK=32, grid 157 (one block per tail tile,
// single round on 256 CUs). Staging: global f32 -> regs -> convert/split ->
// ds_write_b128 (T14 issue-early/write-late). Norms computed f32 in-flight.
// d_ws unused.
//
// LDS per buf (shorts): Ahi[0,4096) Alo[4096,8192) Bhi[8192,10240) Blo[10240,12288)
// Fragment subtile = [16 rows][32 k] shorts = 1KB; a wave's frag read and every
// staging ds_write_b128 cover contiguous 1KB (lane l -> byte l*16): conflict-free.

#define NHEADS 128
#define NCAND  10000
#define EDIM   256
#define BM     128
#define BN     64
#define BK     32
#define KSTEPS (EDIM / BK)   // 8

typedef __attribute__((ext_vector_type(8))) short bf16x8;
typedef __attribute__((ext_vector_type(4))) float f32x4;

__device__ inline unsigned short bf16hi(float x) {   // RNE bf16 truncation
    unsigned int u = __float_as_uint(x);
    return (unsigned short)((u + 0x7FFFu + ((u >> 16) & 1u)) >> 16);
}

__global__ __launch_bounds__(256, 1) void transe_fused(
    const float* __restrict__ entity, const float* __restrict__ relation,
    const int* __restrict__ heads, const int* __restrict__ relations,
    const int* __restrict__ tails, float* __restrict__ out)
{
    __shared__ short sm[2][12288];   // 48 KB
    __shared__ float LPs[BM];
    __shared__ float TNs[BN];

    const int tid = threadIdx.x;
    const int w   = tid >> 6;        // wave 0..3
    const int l   = tid & 63;
    const int n0  = blockIdx.x * BN;

    // ---- staging roles (chunk schema: thread t -> row t>>2, k-chunk (t&3)*8)
    const int arow = tid >> 2;              // A rows arow and arow+64
    const int kco  = (tid & 3) * 8;         // k offset within BK
    // LDS short-offset of (row&63, kco): (t>>6)*512 + ((t>>2)&15)*32 + (t&3)*8
    const int soff = (tid >> 6) * 512 + ((tid >> 2) & 15) * 32 + (tid & 3) * 8;

    const float* __restrict__ ph0 = entity   + (size_t)heads[arow]           * EDIM + kco;
    const float* __restrict__ pr0 = relation + (size_t)relations[arow]       * EDIM + kco;
    const float* __restrict__ ph1 = entity   + (size_t)heads[arow + 64]      * EDIM + kco;
    const float* __restrict__ pr1 = relation + (size_t)relations[arow + 64]  * EDIM + kco;
    int bn = n0 + arow; if (bn > NCAND - 1) bn = NCAND - 1;   // clamp gather only
    const float* __restrict__ pt  = entity + (size_t)tails[bn] * EDIM + kco;

    float xa0[8], xa1[8], xb[8];             // staged f32 (fully unrolled -> regs)
    float an0 = 0.f, an1 = 0.f, bnm = 0.f;   // norm accumulators
    f32x4 acc[2][4] = {};

    auto load_tile = [&](int s) {
        const int k0 = s * BK;
        #pragma unroll
        for (int c = 0; c < 2; ++c) {
            float4 h0 = *(const float4*)(ph0 + k0 + 4 * c);
            float4 r0 = *(const float4*)(pr0 + k0 + 4 * c);
            float4 h1 = *(const float4*)(ph1 + k0 + 4 * c);
            float4 r1 = *(const float4*)(pr1 + k0 + 4 * c);
            float4 bv = *(const float4*)(pt  + k0 + 4 * c);
            xa0[4*c+0] = h0.x + r0.x; xa0[4*c+1] = h0.y + r0.y;
            xa0[4*c+2] = h0.z + r0.z; xa0[4*c+3] = h0.w + r0.w;
            xa1[4*c+0] = h1.x + r1.x; xa1[4*c+1] = h1.y + r1.y;
            xa1[4*c+2] = h1.z + r1.z; xa1[4*c+3] = h1.w + r1.w;
            xb[4*c+0]  = bv.x; xb[4*c+1] = bv.y; xb[4*c+2] = bv.z; xb[4*c+3] = bv.w;
        }
    };

    auto convert_write = [&](int buf) {
        short* base = &sm[buf][0];
        bf16x8 h0, l0, h1, l1, hb, lb;
        #pragma unroll
        for (int j = 0; j < 8; ++j) {
            float x = xa0[j];
            an0 = fmaf(x, x, an0);
            unsigned short hh = bf16hi(x);
            h0[j] = (short)hh;
            l0[j] = (short)bf16hi(x - __uint_as_float((unsigned)hh << 16));
            x = xa1[j];
            an1 = fmaf(x, x, an1);
            hh = bf16hi(x);
            h1[j] = (short)hh;
            l1[j] = (short)bf16hi(x - __uint_as_float((unsigned)hh << 16));
            x = xb[j];
            bnm = fmaf(x, x, bnm);
            hh = bf16hi(x);
            hb[j] = (short)hh;
            lb[j] = (short)bf16hi(x - __uint_as_float((unsigned)hh << 16));
        }
        *(bf16x8*)(base + soff)               = h0;   // A row arow      (rgrp 0..3)
        *(bf16x8*)(base + 2048 + soff)        = h1;   // A row arow+64   (rgrp 4..7)
        *(bf16x8*)(base + 4096 + soff)        = l0;
        *(bf16x8*)(base + 4096 + 2048 + soff) = l1;
        *(bf16x8*)(base + 8192 + soff)        = hb;   // B
        *(bf16x8*)(base + 10240 + soff)       = lb;
    };

    auto compute = [&](int buf) {
        const short* base = &sm[buf][0];
        const int fo = (l & 15) * 32 + (l >> 4) * 8;
        bf16x8 ah[2], al[2];
        #pragma unroll
        for (int mf = 0; mf < 2; ++mf) {
            // wave w: rows 32w..32w+31 -> rgrps 2w, 2w+1 (g*512 valid for g=0..7)
            ah[mf] = *(const bf16x8*)(base + (2 * w + mf) * 512 + fo);
            al[mf] = *(const bf16x8*)(base + 4096 + (2 * w + mf) * 512 + fo);
        }
        #pragma unroll
        for (int nf = 0; nf < 4; ++nf) {
            bf16x8 bh = *(const bf16x8*)(base + 8192  + nf * 512 + fo);
            bf16x8 bl = *(const bf16x8*)(base + 10240 + nf * 512 + fo);
            #pragma unroll
            for (int mf = 0; mf < 2; ++mf) {
                acc[mf][nf] = __builtin_amdgcn_mfma_f32_16x16x32_bf16(ah[mf], bh, acc[mf][nf], 0, 0, 0);
                acc[mf][nf] = __builtin_amdgcn_mfma_f32_16x16x32_bf16(ah[mf], bl, acc[mf][nf], 0, 0, 0);
                acc[mf][nf] = __builtin_amdgcn_mfma_f32_16x16x32_bf16(al[mf], bh, acc[mf][nf], 0, 0, 0);
            }
        }
    };

    // ---- pipeline: loads(t+1) early; convert+write after compute (T14)
    load_tile(0);
    convert_write(0);
    __syncthreads();
    #pragma unroll
    for (int t = 0; t < KSTEPS; ++t) {
        const int buf = t & 1;
        if (t < KSTEPS - 1) load_tile(t + 1);
        compute(buf);
        if (t < KSTEPS - 1) convert_write(buf ^ 1);
        __syncthreads();
    }

    // ---- norms: reduce over the 4 threads sharing a row (same wave: l^1, l^2)
    an0 += __shfl_xor(an0, 1); an0 += __shfl_xor(an0, 2);
    an1 += __shfl_xor(an1, 1); an1 += __shfl_xor(an1, 2);
    bnm += __shfl_xor(bnm, 1); bnm += __shfl_xor(bnm, 2);
    if ((tid & 3) == 0) {
        LPs[arow]      = an0;
        LPs[arow + 64] = an1;
        TNs[arow]      = bnm;    // arow == brow == tid>>2 (0..63)
    }
    __syncthreads();

    // ---- epilogue (m89 C/D layout: col = l&15, row = (l>>4)*4 + r)
    const int cb = l & 15;
    const int rq = l >> 4;
    #pragma unroll
    for (int nf = 0; nf < 4; ++nf) {
        const int col = n0 + 16 * nf + cb;
        if (col < NCAND) {
            const float tn = TNs[16 * nf + cb];
            #pragma unroll
            for (int mf = 0; mf < 2; ++mf) {
                #pragma unroll
                for (int r = 0; r < 4; ++r) {
                    const int m = 32 * w + 16 * mf + rq * 4 + r;
                    const float v = LPs[m] + tn - 2.f * acc[mf][nf][r];
                    out[(size_t)m * NCAND + col] = -sqrtf(fmaxf(v, 0.f));
                }
            }
        }
    }
}

extern "C" void kernel_launch(void* const* d_in, const int* in_sizes, int n_in,
                              void* d_out, int out_size, void* d_ws, size_t ws_size,
                              hipStream_t stream) {
    const float* entity    = (const float*)d_in[0];
    const float* relation  = (const float*)d_in[1];
    const int*   heads     = (const int*)d_in[2];
    const int*   relations = (const int*)d_in[3];
    const int*   tails     = (const int*)d_in[4];
    float*       out       = (float*)d_out;

    transe_fused<<<dim3((NCAND + BN - 1) / BN), dim3(256), 0, stream>>>(
        entity, relation, heads, relations, tails, out);
}